// Round 8
// baseline (103.418 us; speedup 1.0000x reference)
//
#include <hip/hip_runtime.h>
#include <hip/hip_bf16.h>
#include <math.h>

#define NB    4
#define NC    128
#define NPIX  3136      // 56*56
#define CHW   401408    // 128*3136
#define SKS   68        // padded LDS row stride for K/V images
#define STS   19        // conv transpose-buffer row stride (odd => bank-clean)

// ---------- DPP wave64 reduce helpers (VALU pipe, no DS) -------------------
template <int CTRL, int RM>
__device__ __forceinline__ float dpp_mov(float x, float old) {
    return __int_as_float(__builtin_amdgcn_update_dpp(
        __float_as_int(old), __float_as_int(x), CTRL, RM, 0xf, false));
}
__device__ __forceinline__ float wave_max(float x) {
    x = fmaxf(x, dpp_mov<0x111, 0xf>(x, x));   // row_shr:1
    x = fmaxf(x, dpp_mov<0x112, 0xf>(x, x));   // row_shr:2
    x = fmaxf(x, dpp_mov<0x114, 0xf>(x, x));   // row_shr:4
    x = fmaxf(x, dpp_mov<0x118, 0xf>(x, x));   // row_shr:8
    x = fmaxf(x, dpp_mov<0x142, 0xa>(x, x));   // row_bcast:15 -> rows 1,3
    x = fmaxf(x, dpp_mov<0x143, 0xc>(x, x));   // row_bcast:31 -> rows 2,3
    return __int_as_float(__builtin_amdgcn_readlane(__float_as_int(x), 63));
}
__device__ __forceinline__ float wave_sum(float x) {
    x = x + dpp_mov<0x111, 0xf>(x, 0.f);
    x = x + dpp_mov<0x112, 0xf>(x, 0.f);
    x = x + dpp_mov<0x114, 0xf>(x, 0.f);
    x = x + dpp_mov<0x118, 0xf>(x, 0.f);
    x = x + dpp_mov<0x142, 0xa>(x, 0.f);
    x = x + dpp_mov<0x143, 0xc>(x, 0.f);
    return __int_as_float(__builtin_amdgcn_readlane(__float_as_int(x), 63));
}

// ---------------- prep: weight pack + rel sums ------------------------------
__global__ __launch_bounds__(256) void prep_kernel(
    const float* __restrict__ qw, const float* __restrict__ kw,
    const float* __restrict__ vw,
    const float* __restrict__ rel_h, const float* __restrict__ rel_w,
    float* __restrict__ w4q, float* __restrict__ w4k, float* __restrict__ w4v,
    float* __restrict__ rb)
{
    int idx = blockIdx.x * 256 + threadIdx.x;
    if (idx < 3 * 16384) {
        int m = idx >> 14;
        int r = idx & 16383;          // dst-linear: ((c4*128 + o)*4 + cc)
        int cc = r & 3;
        int t = r >> 2;
        int o = t & 127;
        int c4 = t >> 7;
        const float* src = (m == 0) ? qw : (m == 1) ? kw : vw;
        float* dst = (m == 0) ? w4q : (m == 1) ? w4k : w4v;
        dst[r] = src[o * 128 + c4 * 4 + cc];
    }
    if (idx < 14) {
        const float* src = (idx < 7) ? rel_h : rel_w;
        int off = (idx < 7) ? idx : idx - 7;
        float s = 0.f;
        for (int c = 0; c < 64; ++c) s += src[c * 7 + off];
        rb[idx] = s;
    }
}

// FMA block for one input channel ROW with scalar weights WQ/WK/WV
#define CBLK(WQ, WK, WV, ROW) do {                                       \
    const float* xr = sx + (ROW) * 16 + ph;                              \
    float4 xa = *(const float4*)xr;                                      \
    float4 xc = *(const float4*)(xr + 4);                                \
    float xv[8] = {xa.x, xa.y, xa.z, xa.w, xc.x, xc.y, xc.z, xc.w};      \
    _Pragma("unroll")                                                    \
    for (int pp = 0; pp < 8; ++pp) {                                     \
        aq[pp] += (WQ) * xv[pp];                                         \
        ak[pp] += (WK) * xv[pp];                                         \
        av[pp] += (WV) * xv[pp];                                         \
    } } while (0)

// ---------------- conv: fused 1x1 convs Q,K,V (fp32) -----------------------
// lane=o compute with depth-2 A/B weight prefetch; stride-19 LDS transpose;
// lane=pixel coalesced stores; also emits qsum[b][tile][o] for attn.
__global__ __launch_bounds__(256) void conv_kernel(
    const float* __restrict__ x,
    const float* __restrict__ w4q, const float* __restrict__ w4k,
    const float* __restrict__ w4v,
    const float* __restrict__ qb, const float* __restrict__ kb,
    const float* __restrict__ vb,
    float* __restrict__ q, float* __restrict__ kbuf, float* __restrict__ vbuf,
    float* __restrict__ qsum)
{
    __shared__ float sx[128 * 16];       // [c][pix] 8KB
    __shared__ float st[3 * 128 * STS];  // q/k/v transpose planes, 28.5KB
    int bid = blockIdx.x;
    int tile = bid % 196;
    int b = bid / 196;
    int pix0 = tile * 16;
    const float* xb = x + b * CHW + pix0;

    for (int i = threadIdx.x; i < 512; i += 256) {
        int c = i >> 2, p4 = (i & 3) * 4;
        *(float4*)(sx + c * 16 + p4) = *(const float4*)(xb + c * NPIX + p4);
    }
    __syncthreads();

    int lane = threadIdx.x & 63;
    int wave = threadIdx.x >> 6;
    int o = wave * 32 + (lane & 31);
    int ph = (lane >> 5) * 8;
    const float4* Wq = (const float4*)w4q + o;
    const float4* Wk = (const float4*)w4k + o;
    const float4* Wv = (const float4*)w4v + o;

    // depth-2 software pipeline: A holds even channel-block, B odd
    float4 wqA = Wq[0],   wkA = Wk[0],   wvA = Wv[0];
    float4 wqB = Wq[128], wkB = Wk[128], wvB = Wv[128];
    float aq[8] = {}, ak[8] = {}, av[8] = {};
    #pragma unroll 1
    for (int c4 = 0; c4 < 32; c4 += 2) {
        int ia = ((c4 + 2) & 31) * 128;   // masked: tail prefetch harmless
        int ib = ((c4 + 3) & 31) * 128;
        // ---- A: channels 4*c4 .. 4*c4+3 ----
        CBLK(wqA.x, wkA.x, wvA.x, c4 * 4 + 0);
        CBLK(wqA.y, wkA.y, wvA.y, c4 * 4 + 1);
        CBLK(wqA.z, wkA.z, wvA.z, c4 * 4 + 2);
        CBLK(wqA.w, wkA.w, wvA.w, c4 * 4 + 3);
        wqA = Wq[ia]; wkA = Wk[ia]; wvA = Wv[ia];   // reload after last use
        // ---- B: channels 4*c4+4 .. 4*c4+7 ----
        CBLK(wqB.x, wkB.x, wvB.x, c4 * 4 + 4);
        CBLK(wqB.y, wkB.y, wvB.y, c4 * 4 + 5);
        CBLK(wqB.z, wkB.z, wvB.z, c4 * 4 + 6);
        CBLK(wqB.w, wkB.w, wvB.w, c4 * 4 + 7);
        wqB = Wq[ib]; wkB = Wk[ib]; wvB = Wv[ib];
    }
    float bq = qb[o], bk = kb[o], bv = vb[o];

    // qsum[b][tile][o]: sum of q over the 16-pixel tile (== attn group)
    float qp = ((aq[0] + aq[1]) + (aq[2] + aq[3]))
             + ((aq[4] + aq[5]) + (aq[6] + aq[7])) + 8.f * bq;
    qp += __shfl_xor(qp, 32);
    if (lane < 32) qsum[(b * 196 + tile) * 128 + wave * 32 + lane] = qp;

    float* wrq = st + o * STS + ph;
    float* wrk = st + 128 * STS + o * STS + ph;
    float* wrv = st + 2 * 128 * STS + o * STS + ph;
    #pragma unroll
    for (int p = 0; p < 8; ++p) {
        wrq[p] = aq[p] + bq;
        wrk[p] = ak[p] + bk;
        wrv[p] = av[p] + bv;
    }
    __syncthreads();

    int pix = threadIdx.x & 15;
    int o8 = (threadIdx.x >> 4) * 8;
    float* qd = q + b * CHW + pix0 + pix;
    float* kd = kbuf + b * CHW + pix0 + pix;
    float* vd = vbuf + b * CHW + pix0 + pix;
    #pragma unroll
    for (int i = 0; i < 8; ++i) {
        int r = o8 + i;
        qd[r * NPIX] = st[r * STS + pix];
        kd[r * NPIX] = st[128 * STS + r * STS + pix];
        vd[r * NPIX] = st[2 * 128 * STS + r * STS + pix];
    }
}

// ---------------- attn: per-(b,c,row-quarter) local attention --------------
// qsum precomputed by conv; incremental addressing; 2-chain QK/PV;
// q regs reloaded after last use (one-group prefetch distance, no copies).
__global__ __launch_bounds__(256) void attn_kernel(
    const float* __restrict__ q, const float* __restrict__ kbuf,
    const float* __restrict__ vbuf, const float* __restrict__ qsum,
    const float* __restrict__ kb, const float* __restrict__ vb,
    const float* __restrict__ rb, float* __restrict__ out)
{
    __shared__ float sK[20 * SKS];
    __shared__ float sV[21 * SKS];   // row 20 zeroed (read only with w=0)
    __shared__ float sW[4 * 64];
    int bid = blockIdx.x;
    int qpart = bid & 3;
    int bc = bid >> 2;
    int ch = bc & 127;
    int b = bc >> 7;
    const float* qc = q + bc * NPIX + 784 * qpart;
    const float* kc = kbuf + bc * NPIX;
    const float* vc = vbuf + bc * NPIX;
    const float* qsp = qsum + (b * 196 + qpart * 49) * 128 + ch;
    float* oc = out + bc * NPIX + 784 * qpart;
    float kbias = kb[ch], vbias = vb[ch];
    int qr0 = 14 * qpart;

    for (int i = threadIdx.x; i < 20 * 62; i += 256) {
        int yy = i / 62, xx = i - yy * 62;
        int gy = qr0 + yy - 3;
        int gx = xx - 3;
        bool in = (gy >= 0) && (gy < 56) && (gx >= 0) && (gx < 56);
        int off = in ? gy * 56 + gx : 0;
        float kv = in ? kc[off] : kbias;
        float vv = in ? vc[off] : vbias;
        sK[yy * SKS + xx] = kv;
        sV[yy * SKS + xx] = vv;
    }
    for (int i = threadIdx.x; i < SKS; i += 256) sV[20 * SKS + i] = 0.f;

    int lane = threadIdx.x & 63;
    int wave = threadIdx.x >> 6;
    int k2 = min(lane, 48);
    int di = k2 / 7, dj = k2 - di * 7;
    float rbias = rb[di] + rb[7 + dj];
    int koff = di * SKS + dj;
    int t16 = lane & 15, p = lane >> 4;
    float* sWw = sW + wave * 64;

    // prefetch first group's q + qsum (before barrier: global, no LDS dep)
    int ul0 = wave * 16;
    int y0 = 0, x0 = ul0;
    float4 p0 = *(const float4*)(qc + ul0);
    float4 p1 = *(const float4*)(qc + ul0 + 4);
    float4 p2 = *(const float4*)(qc + ul0 + 8);
    float4 p3 = *(const float4*)(qc + ul0 + 12);
    float qsP = qsp[wave * 128];
    __syncthreads();

    for (int gl = wave; gl < 49; gl += 4) {
        // --- QK: 2 accumulator chains, compile-time-offset LDS reads ------
        float acc0, acc1;
        const float* kp = sK + y0 * SKS + x0 + koff;
        if (x0 != 48) {
            acc0  = p0.x * kp[0];   acc1  = p0.y * kp[1];
            acc0 += p0.z * kp[2];   acc1 += p0.w * kp[3];
            acc0 += p1.x * kp[4];   acc1 += p1.y * kp[5];
            acc0 += p1.z * kp[6];   acc1 += p1.w * kp[7];
            acc0 += p2.x * kp[8];   acc1 += p2.y * kp[9];
            acc0 += p2.z * kp[10];  acc1 += p2.w * kp[11];
            acc0 += p3.x * kp[12];  acc1 += p3.y * kp[13];
            acc0 += p3.z * kp[14];  acc1 += p3.w * kp[15];
        } else {
            const float* kp2 = sK + (y0 + 1) * SKS + koff;
            acc0  = p0.x * kp[0];   acc1  = p0.y * kp[1];
            acc0 += p0.z * kp[2];   acc1 += p0.w * kp[3];
            acc0 += p1.x * kp[4];   acc1 += p1.y * kp[5];
            acc0 += p1.z * kp[6];   acc1 += p1.w * kp[7];
            acc0 += p2.x * kp2[0];  acc1 += p2.y * kp2[1];
            acc0 += p2.z * kp2[2];  acc1 += p2.w * kp2[3];
            acc0 += p3.x * kp2[4];  acc1 += p3.y * kp2[5];
            acc0 += p3.z * kp2[6];  acc1 += p3.w * kp2[7];
        }
        float val = (lane < 49) ? (acc0 + acc1 + qsP * rbias) : -1e30f;

        // --- reload q regs for group gl+4 (after last use; latency hidden
        //     under softmax+PV+next-iter top) ------------------------------
        if (gl + 4 < 49) {
            int un = ul0 + 64;
            p0 = *(const float4*)(qc + un);
            p1 = *(const float4*)(qc + un + 4);
            p2 = *(const float4*)(qc + un + 8);
            p3 = *(const float4*)(qc + un + 12);
            qsP = qsp[(gl + 4) * 128];
        }

        // --- softmax over 49 via DPP (VALU pipe) -------------------------
        float mS = wave_max(val);
        float e = __expf(val - mS);
        float sS = wave_sum(e);
        float wgt = e * __builtin_amdgcn_rcpf(sS);
        sWw[lane] = wgt;                       // lanes 49..63 write 0 pad

        // --- PV: lane = (t, ki-row-pair p); 2 chains ----------------------
        int xt = x0 + t16;
        int yt = y0;
        if (xt >= 56) { xt -= 56; ++yt; }
        const float* vbase = sV + yt * SKS + xt + p * (2 * SKS);
        const float* wbase = sWw + p * 14;
        float o0 = 0.f, o1 = 0.f;
        #pragma unroll
        for (int j = 0; j < 7; ++j) o0 += wbase[j] * vbase[j];
        #pragma unroll
        for (int j = 0; j < 7; ++j) o1 += wbase[7 + j] * vbase[SKS + j];
        float oacc = o0 + o1;
        oacc += __shfl_xor(oacc, 16);
        oacc += __shfl_xor(oacc, 32);
        if (lane < 16) oc[ul0 + lane] = oacc;

        // --- advance: ul0 += 64  =>  y0 += 1, x0 += 8 (with carry) --------
        ul0 += 64;
        x0 += 8; y0 += 1;
        if (x0 >= 56) { x0 -= 56; ++y0; }
    }
}

extern "C" void kernel_launch(void* const* d_in, const int* in_sizes, int n_in,
                              void* d_out, int out_size, void* d_ws, size_t ws_size,
                              hipStream_t stream) {
    const float* x     = (const float*)d_in[0];
    const float* qw    = (const float*)d_in[1];
    const float* qb    = (const float*)d_in[2];
    const float* kw    = (const float*)d_in[3];
    const float* kb    = (const float*)d_in[4];
    const float* vw    = (const float*)d_in[5];
    const float* vb    = (const float*)d_in[6];
    const float* rel_h = (const float*)d_in[7];
    const float* rel_w = (const float*)d_in[8];
    float* out = (float*)d_out;

    float* ws   = (float*)d_ws;
    float* kbuf = ws;                    // 1605632
    float* vbuf = kbuf + 1605632;        // 1605632
    float* qbuf = vbuf + 1605632;        // 1605632
    float* w4q  = qbuf + 1605632;        // 16384
    float* w4k  = w4q + 16384;
    float* w4v  = w4k + 16384;
    float* qsm  = w4v + 16384;           // 100352 (4*196*128)
    float* rb   = qsm + 100352;          // 16

    prep_kernel<<<192, 256, 0, stream>>>(qw, kw, vw, rel_h, rel_w,
                                         w4q, w4k, w4v, rb);
    conv_kernel<<<784, 256, 0, stream>>>(x, w4q, w4k, w4v, qb, kb, vb,
                                         qbuf, kbuf, vbuf, qsm);
    attn_kernel<<<2048, 256, 0, stream>>>(qbuf, kbuf, vbuf, qsm, kb, vb, rb, out);
}

// Round 9
// 78.230 us; speedup vs baseline: 1.3220x; 1.3220x over previous
//
#include <hip/hip_runtime.h>
#include <hip/hip_bf16.h>
#include <math.h>

#define NB    4
#define NC    128
#define NPIX  3136      // 56*56
#define CHW   401408    // 128*3136
#define SKS   68        // padded LDS row stride for K/V images
#define CTS   8         // conv pixel-tile
#define STS   9         // conv transpose-buffer row stride (odd => bank-clean)

// ---------- DPP wave64 reduce helpers (VALU pipe, no DS) -------------------
template <int CTRL, int RM>
__device__ __forceinline__ float dpp_mov(float x, float old) {
    return __int_as_float(__builtin_amdgcn_update_dpp(
        __float_as_int(old), __float_as_int(x), CTRL, RM, 0xf, false));
}
__device__ __forceinline__ float wave_max(float x) {
    x = fmaxf(x, dpp_mov<0x111, 0xf>(x, x));   // row_shr:1
    x = fmaxf(x, dpp_mov<0x112, 0xf>(x, x));   // row_shr:2
    x = fmaxf(x, dpp_mov<0x114, 0xf>(x, x));   // row_shr:4
    x = fmaxf(x, dpp_mov<0x118, 0xf>(x, x));   // row_shr:8
    x = fmaxf(x, dpp_mov<0x142, 0xa>(x, x));   // row_bcast:15 -> rows 1,3
    x = fmaxf(x, dpp_mov<0x143, 0xc>(x, x));   // row_bcast:31 -> rows 2,3
    return __int_as_float(__builtin_amdgcn_readlane(__float_as_int(x), 63));
}
__device__ __forceinline__ float wave_sum(float x) {
    x = x + dpp_mov<0x111, 0xf>(x, 0.f);
    x = x + dpp_mov<0x112, 0xf>(x, 0.f);
    x = x + dpp_mov<0x114, 0xf>(x, 0.f);
    x = x + dpp_mov<0x118, 0xf>(x, 0.f);
    x = x + dpp_mov<0x142, 0xa>(x, 0.f);
    x = x + dpp_mov<0x143, 0xc>(x, 0.f);
    return __int_as_float(__builtin_amdgcn_readlane(__float_as_int(x), 63));
}

// 16-term QK dot: 8 reads from kp, 8 from kp2 (kp2=kp+8 unless row-wrap)
__device__ __forceinline__ float qk16(const float* kp, const float* kp2,
                                      float4 r0, float4 r1, float4 r2, float4 r3) {
    float a0, a1;
    a0  = r0.x * kp[0];   a1  = r0.y * kp[1];
    a0 += r0.z * kp[2];   a1 += r0.w * kp[3];
    a0 += r1.x * kp[4];   a1 += r1.y * kp[5];
    a0 += r1.z * kp[6];   a1 += r1.w * kp[7];
    a0 += r2.x * kp2[0];  a1 += r2.y * kp2[1];
    a0 += r2.z * kp2[2];  a1 += r2.w * kp2[3];
    a0 += r3.x * kp2[4];  a1 += r3.y * kp2[5];
    a0 += r3.z * kp2[6];  a1 += r3.w * kp2[7];
    return a0 + a1;
}
__device__ __forceinline__ float sum16(float4 r0, float4 r1, float4 r2, float4 r3) {
    return (((r0.x + r0.y) + (r0.z + r0.w)) + ((r1.x + r1.y) + (r1.z + r1.w)))
         + (((r2.x + r2.y) + (r2.z + r2.w)) + ((r3.x + r3.y) + (r3.z + r3.w)));
}

// ---------------- prep: weight pack + rel sums ------------------------------
__global__ __launch_bounds__(256) void prep_kernel(
    const float* __restrict__ qw, const float* __restrict__ kw,
    const float* __restrict__ vw,
    const float* __restrict__ rel_h, const float* __restrict__ rel_w,
    float* __restrict__ w4q, float* __restrict__ w4k, float* __restrict__ w4v,
    float* __restrict__ rb)
{
    int idx = blockIdx.x * 256 + threadIdx.x;
    if (idx < 3 * 16384) {
        int m = idx >> 14;
        int r = idx & 16383;          // dst-linear: ((c4*128 + o)*4 + cc)
        int cc = r & 3;
        int t = r >> 2;
        int o = t & 127;
        int c4 = t >> 7;
        const float* src = (m == 0) ? qw : (m == 1) ? kw : vw;
        float* dst = (m == 0) ? w4q : (m == 1) ? w4k : w4v;
        dst[r] = src[o * 128 + c4 * 4 + cc];
    }
    if (idx < 14) {
        const float* src = (idx < 7) ? rel_h : rel_w;
        int off = (idx < 7) ? idx : idx - 7;
        float s = 0.f;
        for (int c = 0; c < 64; ++c) s += src[c * 7 + off];
        rb[idx] = s;
    }
}

// ---------------- conv: fused 1x1 convs Q,K,V (fp32) -----------------------
// r7 structure, tile=8 pixels -> grid 1568 (6 waves/SIMD). lane=o compute
// (coalesced W4 loads, depth-1 prefetch, batched x reads); stride-9 LDS
// transpose; lane=pixel coalesced stores to unpadded q/k/v.
__global__ __launch_bounds__(256) void conv_kernel(
    const float* __restrict__ x,
    const float* __restrict__ w4q, const float* __restrict__ w4k,
    const float* __restrict__ w4v,
    const float* __restrict__ qb, const float* __restrict__ kb,
    const float* __restrict__ vb,
    float* __restrict__ q, float* __restrict__ kbuf, float* __restrict__ vbuf)
{
    __shared__ float sx[128 * CTS];       // [c][pix] 4KB
    __shared__ float st[3 * 128 * STS];   // q/k/v transpose planes, 13.8KB
    int bid = blockIdx.x;
    int tile = bid % 392;
    int b = bid / 392;
    int pix0 = tile * CTS;
    const float* xb = x + b * CHW + pix0;

    {   // 256 float4 loads, one per thread
        int c = threadIdx.x >> 1, p4 = (threadIdx.x & 1) * 4;
        *(float4*)(sx + c * CTS + p4) = *(const float4*)(xb + c * NPIX + p4);
    }
    __syncthreads();

    int lane = threadIdx.x & 63;
    int wave = threadIdx.x >> 6;
    int o = wave * 32 + (lane & 31);
    int ph = (lane >> 5) * 4;
    const float4* Wq = (const float4*)w4q + o;
    const float4* Wk = (const float4*)w4k + o;
    const float4* Wv = (const float4*)w4v + o;

    float4 wqc = Wq[0], wkc = Wk[0], wvc = Wv[0];   // depth-1 pipeline head
    float aq[4] = {}, ak[4] = {}, av[4] = {};
    #pragma unroll 1
    for (int c4 = 0; c4 < 32; ++c4) {
        float4 xs[4];
        #pragma unroll
        for (int cc = 0; cc < 4; ++cc)
            xs[cc] = *(const float4*)(sx + (c4 * 4 + cc) * CTS + ph);
        float4 wq4 = wqc, wk4 = wkc, wv4 = wvc;
        if (c4 < 31) {   // prefetch next iter's weights
            wqc = Wq[(c4 + 1) * 128];
            wkc = Wk[(c4 + 1) * 128];
            wvc = Wv[(c4 + 1) * 128];
        }
        float wqr[4] = {wq4.x, wq4.y, wq4.z, wq4.w};
        float wkr[4] = {wk4.x, wk4.y, wk4.z, wk4.w};
        float wvr[4] = {wv4.x, wv4.y, wv4.z, wv4.w};
        #pragma unroll
        for (int cc = 0; cc < 4; ++cc) {
            float xv[4] = {xs[cc].x, xs[cc].y, xs[cc].z, xs[cc].w};
            #pragma unroll
            for (int p = 0; p < 4; ++p) {
                aq[p] += wqr[cc] * xv[p];
                ak[p] += wkr[cc] * xv[p];
                av[p] += wvr[cc] * xv[p];
            }
        }
    }
    float bq = qb[o], bk = kb[o], bv = vb[o];
    float* wrq = st + o * STS + ph;
    float* wrk = st + 128 * STS + o * STS + ph;
    float* wrv = st + 2 * 128 * STS + o * STS + ph;
    #pragma unroll
    for (int p = 0; p < 4; ++p) {
        wrq[p] = aq[p] + bq;
        wrk[p] = ak[p] + bk;
        wrv[p] = av[p] + bv;
    }
    __syncthreads();

    int pix = threadIdx.x & 7;
    int o4 = (threadIdx.x >> 3) * 4;
    float* qd = q + b * CHW + pix0 + pix;
    float* kd = kbuf + b * CHW + pix0 + pix;
    float* vd = vbuf + b * CHW + pix0 + pix;
    #pragma unroll
    for (int i = 0; i < 4; ++i) {
        int r = o4 + i;
        qd[r * NPIX] = st[r * STS + pix];
        kd[r * NPIX] = st[128 * STS + r * STS + pix];
        vd[r * NPIX] = st[2 * 128 * STS + r * STS + pix];
    }
}

// ---------------- attn: per-(b,c,row-quarter), 2 groups per wave-iter ------
// Wave w handles pairs (2w+8i, 2w+8i+1), i=0..5; wave 0 also does group 48.
// Twin chains double ILP on QK/softmax/PV; q regs reloaded after last use.
__global__ __launch_bounds__(256) void attn_kernel(
    const float* __restrict__ q, const float* __restrict__ kbuf,
    const float* __restrict__ vbuf,
    const float* __restrict__ kb, const float* __restrict__ vb,
    const float* __restrict__ rb, float* __restrict__ out)
{
    __shared__ float sK[20 * SKS];
    __shared__ float sV[21 * SKS];   // row 20 zeroed (read only with w=0)
    __shared__ float sW[4 * 128];    // per wave: [A 64][B 64]
    int bid = blockIdx.x;
    int qpart = bid & 3;
    int bc = bid >> 2;
    int ch = bc & 127;
    const float* qc = q + bc * NPIX + 784 * qpart;
    const float* kc = kbuf + bc * NPIX;
    const float* vc = vbuf + bc * NPIX;
    float* oc = out + bc * NPIX + 784 * qpart;
    float kbias = kb[ch], vbias = vb[ch];
    int qr0 = 14 * qpart;

    for (int i = threadIdx.x; i < 20 * 62; i += 256) {
        int yy = i / 62, xx = i - yy * 62;
        int gy = qr0 + yy - 3;
        int gx = xx - 3;
        bool in = (gy >= 0) && (gy < 56) && (gx >= 0) && (gx < 56);
        int off = in ? gy * 56 + gx : 0;
        float kv = in ? kc[off] : kbias;
        float vv = in ? vc[off] : vbias;
        sK[yy * SKS + xx] = kv;
        sV[yy * SKS + xx] = vv;
    }
    for (int i = threadIdx.x; i < SKS; i += 256) sV[20 * SKS + i] = 0.f;

    int lane = threadIdx.x & 63;
    int wave = threadIdx.x >> 6;
    int k2 = min(lane, 48);
    int di = k2 / 7, dj = k2 - di * 7;
    float rbias = rb[di] + rb[7 + dj];
    int koff = di * SKS + dj;
    int t16 = lane & 15, p = lane >> 4;
    float* sWA = sW + wave * 128;
    float* sWB = sWA + 64;

    // initial pair prefetch (global loads, no LDS dep -> before barrier)
    int ulA = wave * 32;
    int y0 = (ulA >= 56) ? 1 : 0;
    int x0 = ulA - y0 * 56;
    float4 a0 = *(const float4*)(qc + ulA);
    float4 a1 = *(const float4*)(qc + ulA + 4);
    float4 a2 = *(const float4*)(qc + ulA + 8);
    float4 a3 = *(const float4*)(qc + ulA + 12);
    float4 b0 = *(const float4*)(qc + ulA + 16);
    float4 b1 = *(const float4*)(qc + ulA + 20);
    float4 b2 = *(const float4*)(qc + ulA + 24);
    float4 b3 = *(const float4*)(qc + ulA + 28);
    __syncthreads();

    #pragma unroll 1
    for (int it = 0; it < 6; ++it) {
        int xB = x0 + 16, yB = y0;
        if (xB >= 56) { xB -= 56; ++yB; }

        const float* kpA = sK + y0 * SKS + x0 + koff;
        const float* kpA2 = (x0 == 48) ? (sK + (y0 + 1) * SKS + koff) : (kpA + 8);
        const float* kpB = sK + yB * SKS + xB + koff;
        const float* kpB2 = (xB == 48) ? (sK + (yB + 1) * SKS + koff) : (kpB + 8);

        float qsA = sum16(a0, a1, a2, a3);
        float qsB = sum16(b0, b1, b2, b3);
        float accA = qk16(kpA, kpA2, a0, a1, a2, a3);
        float accB = qk16(kpB, kpB2, b0, b1, b2, b3);
        float valA = (lane < 49) ? (accA + qsA * rbias) : -1e30f;
        float valB = (lane < 49) ? (accB + qsB * rbias) : -1e30f;

        int ulCur = ulA;
        // reload q regs for next pair (after last use; hidden under softmax+PV)
        if (it < 5) {
            int un = ulA + 128;
            a0 = *(const float4*)(qc + un);
            a1 = *(const float4*)(qc + un + 4);
            a2 = *(const float4*)(qc + un + 8);
            a3 = *(const float4*)(qc + un + 12);
            b0 = *(const float4*)(qc + un + 16);
            b1 = *(const float4*)(qc + un + 20);
            b2 = *(const float4*)(qc + un + 24);
            b3 = *(const float4*)(qc + un + 28);
        } else if (wave == 0) {   // tail: group 48 q into A regs
            a0 = *(const float4*)(qc + 768);
            a1 = *(const float4*)(qc + 772);
            a2 = *(const float4*)(qc + 776);
            a3 = *(const float4*)(qc + 780);
        }

        // twin softmax (independent DPP chains interleave on VALU)
        float mA = wave_max(valA);
        float mB = wave_max(valB);
        float eA = __expf(valA - mA);
        float eB = __expf(valB - mB);
        float sA = wave_sum(eA);
        float sB = wave_sum(eB);
        sWA[lane] = eA * __builtin_amdgcn_rcpf(sA);
        sWB[lane] = eB * __builtin_amdgcn_rcpf(sB);

        // twin PV
        int xtA = x0 + t16, ytA = y0;
        if (xtA >= 56) { xtA -= 56; ++ytA; }
        int xtB = xB + t16, ytB = yB;
        if (xtB >= 56) { xtB -= 56; ++ytB; }
        const float* vbA = sV + ytA * SKS + xtA + p * (2 * SKS);
        const float* vbB = sV + ytB * SKS + xtB + p * (2 * SKS);
        const float* wbA = sWA + p * 14;
        const float* wbB = sWB + p * 14;
        float oA0 = 0.f, oA1 = 0.f, oB0 = 0.f, oB1 = 0.f;
        #pragma unroll
        for (int j = 0; j < 7; ++j) {
            oA0 += wbA[j] * vbA[j];
            oB0 += wbB[j] * vbB[j];
            oA1 += wbA[7 + j] * vbA[SKS + j];
            oB1 += wbB[7 + j] * vbB[SKS + j];
        }
        float oaccA = oA0 + oA1, oaccB = oB0 + oB1;
        oaccA += __shfl_xor(oaccA, 16);
        oaccB += __shfl_xor(oaccB, 16);
        oaccA += __shfl_xor(oaccA, 32);
        oaccB += __shfl_xor(oaccB, 32);
        if (lane < 16) {
            oc[ulCur + lane] = oaccA;
            oc[ulCur + 16 + lane] = oaccB;
        }

        ulA += 128; x0 += 16; y0 += 2;
        if (x0 >= 56) { x0 -= 56; ++y0; }
    }

    if (wave == 0) {   // group 48: (y,x) = (13,40); no row-wrap anywhere
        const float* kp = sK + 13 * SKS + 40 + koff;
        float qs = sum16(a0, a1, a2, a3);
        float acc = qk16(kp, kp + 8, a0, a1, a2, a3);
        float val = (lane < 49) ? (acc + qs * rbias) : -1e30f;
        float m = wave_max(val);
        float e = __expf(val - m);
        float s = wave_sum(e);
        sWA[lane] = e * __builtin_amdgcn_rcpf(s);
        const float* vb_ = sV + 13 * SKS + 40 + t16 + p * (2 * SKS);
        const float* wb_ = sWA + p * 14;
        float o0 = 0.f, o1 = 0.f;
        #pragma unroll
        for (int j = 0; j < 7; ++j) {
            o0 += wb_[j] * vb_[j];
            o1 += wb_[7 + j] * vb_[SKS + j];
        }
        float oacc = o0 + o1;
        oacc += __shfl_xor(oacc, 16);
        oacc += __shfl_xor(oacc, 32);
        if (lane < 16) oc[768 + lane] = oacc;
    }
}

extern "C" void kernel_launch(void* const* d_in, const int* in_sizes, int n_in,
                              void* d_out, int out_size, void* d_ws, size_t ws_size,
                              hipStream_t stream) {
    const float* x     = (const float*)d_in[0];
    const float* qw    = (const float*)d_in[1];
    const float* qb    = (const float*)d_in[2];
    const float* kw    = (const float*)d_in[3];
    const float* kb    = (const float*)d_in[4];
    const float* vw    = (const float*)d_in[5];
    const float* vb    = (const float*)d_in[6];
    const float* rel_h = (const float*)d_in[7];
    const float* rel_w = (const float*)d_in[8];
    float* out = (float*)d_out;

    float* ws   = (float*)d_ws;
    float* kbuf = ws;                    // 1605632
    float* vbuf = kbuf + 1605632;        // 1605632
    float* qbuf = vbuf + 1605632;        // 1605632
    float* w4q  = qbuf + 1605632;        // 16384
    float* w4k  = w4q + 16384;
    float* w4v  = w4k + 16384;
    float* rb   = w4v + 16384;           // 16

    prep_kernel<<<192, 256, 0, stream>>>(qw, kw, vw, rel_h, rel_w,
                                         w4q, w4k, w4v, rb);
    conv_kernel<<<1568, 256, 0, stream>>>(x, w4q, w4k, w4v, qb, kb, vb,
                                          qbuf, kbuf, vbuf);
    attn_kernel<<<2048, 256, 0, stream>>>(qbuf, kbuf, vbuf, kb, vb, rb, out);
}